// Round 9
// baseline (418.284 us; speedup 1.0000x reference)
//
#include <hip/hip_runtime.h>
#include <hip/hip_bf16.h>

#define B_  2
#define T_  2048
#define D_  2048
#define H_  16
#define HD_ 128
#define NT_ 4096   // B*T
#define D3_ 6144   // 3*D

typedef __bf16 bf16;
typedef _Float16 f16;
typedef bf16 bf16x2 __attribute__((ext_vector_type(2)));
typedef bf16 bf16x4 __attribute__((ext_vector_type(4)));
typedef bf16 bf16x8 __attribute__((ext_vector_type(8)));
typedef f16  f16x2  __attribute__((ext_vector_type(2)));
typedef f16  f16x4  __attribute__((ext_vector_type(4)));
typedef float floatx4 __attribute__((ext_vector_type(4)));

__device__ __forceinline__ void gl_lds16(const void* g, void* l) {
    __builtin_amdgcn_global_load_lds((const __attribute__((address_space(1))) void*)g,
                                     (__attribute__((address_space(3))) void*)l, 16, 0, 0);
}

// ---------------- fused prep: x->bf16, Wqkv^T->bf16, Wproj^T->bf16 ----------------
__global__ __launch_bounds__(256) void k_prep(const float* __restrict__ x,
                                              const float* __restrict__ Wqkv, const float* __restrict__ Wproj,
                                              bf16* __restrict__ xb, bf16* __restrict__ WqkvT, bf16* __restrict__ WprojT) {
    int blk = blockIdx.x;
    int tid = threadIdx.x;
    if (blk < 8192) {   // x convert: 8192*256*4 = 8M elems
        int i = blk * 256 + tid;
        float4 v = ((const float4*)x)[i];
        bf16x4 o = { (bf16)v.x, (bf16)v.y, (bf16)v.z, (bf16)v.w };
        ((bf16x4*)xb)[i] = o;
        return;
    }
    __shared__ float tile[64][65];
    const float* in; bf16* out; int C, bx;
    if (blk < 8192 + 3072) { bx = blk - 8192; in = Wqkv; out = WqkvT; C = D3_; }
    else                   { bx = blk - 8192 - 3072; in = Wproj; out = WprojT; C = D_; }
    const int R = D_;
    int nbx = C / 64;
    int c0 = (bx % nbx) * 64, r0 = (bx / nbx) * 64;
#pragma unroll
    for (int i = 0; i < 16; i++) {
        int idx = tid + i * 256, r = idx >> 6, c = idx & 63;
        tile[r][c] = in[(size_t)(r0 + r) * C + (c0 + c)];
    }
    __syncthreads();
#pragma unroll
    for (int i = 0; i < 16; i++) {
        int idx = tid + i * 256, r = idx >> 6, c = idx & 63;
        out[(size_t)(c0 + r) * R + (r0 + c)] = (bf16)tile[c][r];
    }
}

// ---------------- QKV GEMM with fused RoPE + scatter epilogue (R4/R7 form) ----------------
__global__ __launch_bounds__(256) void k_gemm_qkv(const bf16* __restrict__ A, const bf16* __restrict__ Bt,
                                                  const float* __restrict__ cosp, const float* __restrict__ sinp,
                                                  bf16* __restrict__ Qg, bf16* __restrict__ Kg, f16* __restrict__ VTg) {
    __shared__ bf16 As[128 * 32];
    __shared__ bf16 Bs[128 * 32];
    __shared__ bf16 stage[128 * 130];
    const int tid = threadIdx.x, w = tid >> 6, lane = tid & 63;
    const int quad = lane >> 4, l16 = lane & 15;
    const int n0 = blockIdx.x * 128, m0 = blockIdx.y * 128;
    const int wr = (w >> 1) * 64, wc = (w & 1) * 64;
    const int srow = lane >> 2, schunk = (lane & 3) ^ ((lane >> 2) & 3);
    const bf16* Aw = A + (size_t)m0 * D_ + (size_t)(w * 32 + srow) * D_ + schunk * 8;
    const bf16* Bw = Bt + (size_t)n0 * D_ + (size_t)(w * 32 + srow) * D_ + schunk * 8;
    const int co = (quad ^ (l16 & 3)) * 8;
    const bf16* Abase = As + (wr + l16) * 32 + co;
    const bf16* Bbase = Bs + (wc + l16) * 32 + co;
    floatx4 acc[4][4] = {};
    for (int k0 = 0; k0 < D_; k0 += 32) {
        __syncthreads();
#pragma unroll
        for (int i = 0; i < 2; i++) {
            gl_lds16(Aw + k0 + i * 16 * D_, As + (w * 2 + i) * 512);
            gl_lds16(Bw + k0 + i * 16 * D_, Bs + (w * 2 + i) * 512);
        }
        __syncthreads();
        bf16x8 af[4], bfr[4];
#pragma unroll
        for (int mt = 0; mt < 4; mt++) af[mt] = *(const bf16x8*)(Abase + mt * 512);
#pragma unroll
        for (int nt = 0; nt < 4; nt++) bfr[nt] = *(const bf16x8*)(Bbase + nt * 512);
#pragma unroll
        for (int mt = 0; mt < 4; mt++)
#pragma unroll
            for (int nt = 0; nt < 4; nt++)
                acc[mt][nt] = __builtin_amdgcn_mfma_f32_16x16x32_bf16(af[mt], bfr[nt], acc[mt][nt], 0, 0, 0);
    }
    // stage C tile (bf16) into LDS
    __syncthreads();
#pragma unroll
    for (int mt = 0; mt < 4; mt++)
#pragma unroll
        for (int nt = 0; nt < 4; nt++)
#pragma unroll
            for (int r = 0; r < 4; r++)
                stage[(wr + mt * 16 + quad * 4 + r) * 130 + wc + nt * 16 + l16] = (bf16)acc[mt][nt][r];
    __syncthreads();
    const int type = n0 >> 11, h = (n0 & 2047) >> 7;
    const int b = m0 >> 11, t0 = m0 & 2047;
    if (type < 2) {
        bf16* out = (type == 0 ? Qg : Kg) + ((size_t)(b * H_ + h) * T_ + t0) * HD_;
#pragma unroll
        for (int it = 0; it < 32; it++) {
            int idx = it * 256 + tid, tl = idx >> 6, i = idx & 63;
            float c = cosp[(t0 + tl) * 64 + i], s = sinp[(t0 + tl) * 64 + i];
            float x1 = (float)stage[tl * 130 + i], x2 = (float)stage[tl * 130 + 64 + i];
            bf16x2 o = { (bf16)(x1 * c - x2 * s), (bf16)(x1 * s + x2 * c) };
            *(bf16x2*)(out + (size_t)tl * HD_ + 2 * i) = o;
        }
    } else {
        f16* out = VTg + (size_t)(b * H_ + h) * HD_ * T_ + t0;
#pragma unroll
        for (int it = 0; it < 32; it++) {
            int idx = it * 256 + tid, d = idx >> 6, tp = (idx & 63) * 2;
            f16x2 o = { (f16)(float)stage[tp * 130 + d], (f16)(float)stage[(tp + 1) * 130 + d] };
            *(f16x2*)(out + (size_t)d * T_ + tp) = o;
        }
    }
}

// ---------------- bf16 GEMM: C[MxN] = A[MxK] * Bt[NxK]^T (proj) — R4 form ----------------
template <typename OutT>
__global__ __launch_bounds__(256) void k_gemm_bt(const bf16* __restrict__ A, const bf16* __restrict__ Bt,
                                                 OutT* __restrict__ C, int M, int N, int K) {
    __shared__ bf16 As[128 * 32];
    __shared__ bf16 Bs[128 * 32];
    const int tid = threadIdx.x, w = tid >> 6, lane = tid & 63;
    const int quad = lane >> 4, l16 = lane & 15;
    const int n0 = blockIdx.x * 128, m0 = blockIdx.y * 128;
    const int wr = (w >> 1) * 64, wc = (w & 1) * 64;
    const bf16* Ab = A + (size_t)m0 * K;
    const bf16* Bb = Bt + (size_t)n0 * K;
    const int srow = lane >> 2, scol = (lane & 3) * 8;
    floatx4 acc[4][4] = {};
    for (int k0 = 0; k0 < K; k0 += 32) {
        __syncthreads();
#pragma unroll
        for (int i = 0; i < 2; i++) {
            int ch = w * 2 + i;
            gl_lds16(Ab + (size_t)(ch * 16 + srow) * K + k0 + scol, As + ch * 512);
            gl_lds16(Bb + (size_t)(ch * 16 + srow) * K + k0 + scol, Bs + ch * 512);
        }
        __syncthreads();
        bf16x8 af[4], bfr[4];
#pragma unroll
        for (int mt = 0; mt < 4; mt++) af[mt] = *(const bf16x8*)(As + (wr + mt * 16 + l16) * 32 + quad * 8);
#pragma unroll
        for (int nt = 0; nt < 4; nt++) bfr[nt] = *(const bf16x8*)(Bs + (wc + nt * 16 + l16) * 32 + quad * 8);
#pragma unroll
        for (int mt = 0; mt < 4; mt++)
#pragma unroll
            for (int nt = 0; nt < 4; nt++)
                acc[mt][nt] = __builtin_amdgcn_mfma_f32_16x16x32_bf16(af[mt], bfr[nt], acc[mt][nt], 0, 0, 0);
    }
#pragma unroll
    for (int mt = 0; mt < 4; mt++)
#pragma unroll
        for (int nt = 0; nt < 4; nt++)
#pragma unroll
            for (int r = 0; r < 4; r++) {
                int row = m0 + wr + mt * 16 + quad * 4 + r;
                int col = n0 + wc + nt * 16 + l16;
                C[(size_t)row * N + col] = (OutT)acc[mt][nt][r];
            }
}

// ---------------- Flash attention: double-buffered K/V, ONE barrier per kt ----------------
// Loop shape: sync -> prefetch(kt+1 into alt buf) -> compute(kt). The barrier's vmcnt
// drain hits loads that had a full compute phase to land -> true load/compute overlap.
// ntlim skips fully-masked diagonal chunks (wave-uniform branch).
// NOTE: K staging swizzle must use the per-ch row (row = ch*4 + lane/16): row&7 includes
// the ch*4 term (R8 bug: hoisting dropped it -> scrambled K for odd ch).
__global__ __launch_bounds__(256, 2) void k_flash(const bf16* __restrict__ Qg, const bf16* __restrict__ Kg,
                                                  const f16* __restrict__ VTg, bf16* __restrict__ Og) {
    __shared__ bf16 Ksh[2][64 * 128];   // K tile: 64 t x 128 d, XOR-swizzled 16B chunks
    __shared__ f16  Vsh[2][128 * 64];   // V^T tile: 128 d x 64 t, XOR-swizzled
    const int b1 = blockIdx.x;
    const int bh = b1 & 31;
    const int qt = (b1 < 256) ? (15 - (b1 >> 5)) : ((b1 - 256) >> 5);
    const int tid = threadIdx.x, w = tid >> 6, lane = tid & 63;
    const int quad = lane >> 4, l16 = lane & 15;
    const float scale2 = 0.08838834764831845f * 1.4426950408889634f;  // (1/sqrt(128))*log2(e)
    const int wrow = w * 32;
    const bf16* Qb = Qg + ((size_t)bh * T_ + qt * 128) * HD_;
    bf16x8 qf[2][4];
#pragma unroll
    for (int mt = 0; mt < 2; mt++)
#pragma unroll
        for (int kc = 0; kc < 4; kc++)
            qf[mt][kc] = *(const bf16x8*)(Qb + (size_t)(wrow + mt * 16 + l16) * HD_ + kc * 32 + quad * 8);
    floatx4 oaccT[8][2] = {};   // [d-tile][q-tile]: col=l16=query, row=quad*4+r=d
    float lsum[2] = { 0.f, 0.f };
    const int nkt = 2 * (qt + 1);
    const bf16* Kt0 = Kg + (size_t)bh * T_ * HD_;
    const f16*  Vt0 = VTg + (size_t)bh * HD_ * T_;
    const int vrow_i = lane >> 3, vc_st = ((lane & 7) ^ (lane >> 3)) * 8;   // V: row=ch*8+vrow_i, row&7==vrow_i
    // prologue: stage kt=0 into buf 0
#pragma unroll
    for (int i = 0; i < 4; i++) {
        int ch = w * 4 + i;
        int krow = ch * 4 + (lane >> 4);
        gl_lds16(Kt0 + (size_t)krow * HD_ + ((lane & 15) ^ (krow & 7)) * 8, &Ksh[0][ch * 512]);
        gl_lds16(Vt0 + (size_t)(ch * 8 + vrow_i) * T_ + vc_st, &Vsh[0][ch * 512]);
    }
    for (int kt = 0; kt < nkt; kt++) {
        const int cur = kt & 1;
        __syncthreads();    // loads(kt) landed (issued a full phase ago); prior compute done
        if (kt + 1 < nkt) {
            const bf16* Kt = Kt0 + (size_t)(kt + 1) * 64 * HD_;
            const f16*  Vt = Vt0 + (kt + 1) * 64;
            bf16* Kd = &Ksh[cur ^ 1][0];
            f16*  Vd = &Vsh[cur ^ 1][0];
#pragma unroll
            for (int i = 0; i < 4; i++) {
                int ch = w * 4 + i;
                int krow = ch * 4 + (lane >> 4);
                gl_lds16(Kt + (size_t)krow * HD_ + ((lane & 15) ^ (krow & 7)) * 8, Kd + ch * 512);
                gl_lds16(Vt + (size_t)(ch * 8 + vrow_i) * T_ + vc_st, Vd + ch * 512);
            }
        }
        const bf16* Kb = &Ksh[cur][0];
        const f16*  Vb = &Vsh[cur][0];
        const bool diag = (kt >= 2 * qt);
        const int kb = (kt - 2 * qt) * 64;   // local key base within q-tile (valid when diag)
        const int ntlim = diag ? (((wrow + 31 - kb) >> 4) + 1 < 0 ? 0
                                  : (((wrow + 31 - kb) >> 4) + 1 > 4 ? 4 : ((wrow + 31 - kb) >> 4) + 1))
                               : 4;
        f16x4 pf[2][4];
#pragma unroll
        for (int nt = 0; nt < 4; nt++) {
            if (nt >= ntlim) continue;   // wave-uniform skip of fully-masked chunks
            floatx4 s0 = {}, s1 = {};
#pragma unroll
            for (int kc = 0; kc < 4; kc++) {
                bf16x8 kf = *(const bf16x8*)(Kb + (nt * 16 + l16) * 128 + (((kc * 4 + quad) ^ (l16 & 7)) * 8));
                s0 = __builtin_amdgcn_mfma_f32_16x16x32_bf16(kf, qf[0][kc], s0, 0, 0, 0);
                s1 = __builtin_amdgcn_mfma_f32_16x16x32_bf16(kf, qf[1][kc], s1, 0, 0, 0);
            }
#pragma unroll
            for (int r = 0; r < 4; r++) {
                float v0 = s0[r] * scale2, v1 = s1[r] * scale2;
                if (diag) {
                    int gk = kt * 64 + nt * 16 + quad * 4 + r;
                    if (gk > qt * 128 + wrow + l16) v0 = -1e30f;
                    if (gk > qt * 128 + wrow + 16 + l16) v1 = -1e30f;
                }
                float p0 = exp2f(v0), p1 = exp2f(v1);
                lsum[0] += p0; lsum[1] += p1;
                pf[0][nt][r] = (f16)p0; pf[1][nt][r] = (f16)p1;
            }
        }
        // O^T += V^T P^T  (16x16x16 f16 MFMA)
#pragma unroll
        for (int nt = 0; nt < 4; nt++) {
            if (nt >= ntlim) continue;
#pragma unroll
            for (int dt = 0; dt < 8; dt++) {
                int row = dt * 16 + l16;
                f16x4 vf = *(const f16x4*)(Vb + row * 64 + (((nt * 2 + (quad >> 1)) ^ (row & 7)) * 8) + (quad & 1) * 4);
#pragma unroll
                for (int mt = 0; mt < 2; mt++)
                    oaccT[dt][mt] = __builtin_amdgcn_mfma_f32_16x16x16f16(vf, pf[mt][nt], oaccT[dt][mt], 0, 0, 0);
            }
        }
    }
    // epilogue: reduce lsum across quads (query = l16 fixed), normalize, write (b,t,h,d)
    const int b = bh >> 4, h = bh & 15;
    float inv[2];
#pragma unroll
    for (int mt = 0; mt < 2; mt++) {
        float l = lsum[mt];
        l += __shfl_xor(l, 16);
        l += __shfl_xor(l, 32);
        inv[mt] = 1.0f / l;
    }
#pragma unroll
    for (int mt = 0; mt < 2; mt++) {
        int t = qt * 128 + wrow + mt * 16 + l16;
#pragma unroll
        for (int dt = 0; dt < 8; dt++) {
            bf16x4 o;
#pragma unroll
            for (int r = 0; r < 4; r++) o[r] = (bf16)(oaccT[dt][mt][r] * inv[mt]);
            int c = h * HD_ + dt * 16 + quad * 4;
            *(bf16x4*)(Og + (size_t)(b * T_ + t) * D_ + c) = o;
        }
    }
}

extern "C" void kernel_launch(void* const* d_in, const int* in_sizes, int n_in,
                              void* d_out, int out_size, void* d_ws, size_t ws_size,
                              hipStream_t stream) {
    const float* x     = (const float*)d_in[0];
    const float* cosp  = (const float*)d_in[1];
    const float* sinp  = (const float*)d_in[2];
    const float* Wqkv  = (const float*)d_in[3];
    const float* Wproj = (const float*)d_in[4];
    float* out = (float*)d_out;
    char* ws = (char*)d_ws;
    // workspace layout (96 MB total)
    bf16* xb     = (bf16*)(ws);                          // 16 MB (reused as O after GEMM1)
    bf16* WqkvT  = (bf16*)(ws + (size_t)(16u << 20));    // 24 MB
    bf16* WprojT = (bf16*)(ws + (size_t)(40u << 20));    //  8 MB
    bf16* Qg     = (bf16*)(ws + (size_t)(48u << 20));    // 16 MB
    bf16* Kg     = (bf16*)(ws + (size_t)(64u << 20));    // 16 MB
    f16*  VTg    = (f16*) (ws + (size_t)(80u << 20));    // 16 MB
    bf16* Og     = xb;

    k_prep<<<dim3(8192 + 3072 + 1024), 256, 0, stream>>>(x, Wqkv, Wproj, xb, WqkvT, WprojT);
    k_gemm_qkv<<<dim3(D3_ / 128, NT_ / 128), 256, 0, stream>>>(xb, WqkvT, cosp, sinp, Qg, Kg, VTg);
    k_flash<<<dim3(512), 256, 0, stream>>>(Qg, Kg, VTg, Og);
    k_gemm_bt<float><<<dim3(D_ / 128, NT_ / 128), 256, 0, stream>>>(Og, WprojT, out, NT_, D_, D_);
}

// Round 10
// 373.734 us; speedup vs baseline: 1.1192x; 1.1192x over previous
//
#include <hip/hip_runtime.h>
#include <hip/hip_bf16.h>

#define B_  2
#define T_  2048
#define D_  2048
#define H_  16
#define HD_ 128
#define NT_ 4096   // B*T
#define D3_ 6144   // 3*D

typedef __bf16 bf16;
typedef _Float16 f16;
typedef bf16 bf16x2 __attribute__((ext_vector_type(2)));
typedef bf16 bf16x4 __attribute__((ext_vector_type(4)));
typedef bf16 bf16x8 __attribute__((ext_vector_type(8)));
typedef f16  f16x2  __attribute__((ext_vector_type(2)));
typedef f16  f16x4  __attribute__((ext_vector_type(4)));
typedef float floatx4 __attribute__((ext_vector_type(4)));

__device__ __forceinline__ void gl_lds16(const void* g, void* l) {
    __builtin_amdgcn_global_load_lds((const __attribute__((address_space(1))) void*)g,
                                     (__attribute__((address_space(3))) void*)l, 16, 0, 0);
}

// ---------------- fused prep: x->bf16, Wqkv^T->bf16, Wproj^T->bf16 ----------------
__global__ __launch_bounds__(256) void k_prep(const float* __restrict__ x,
                                              const float* __restrict__ Wqkv, const float* __restrict__ Wproj,
                                              bf16* __restrict__ xb, bf16* __restrict__ WqkvT, bf16* __restrict__ WprojT) {
    int blk = blockIdx.x;
    int tid = threadIdx.x;
    if (blk < 8192) {   // x convert: 8192*256*4 = 8M elems
        int i = blk * 256 + tid;
        float4 v = ((const float4*)x)[i];
        bf16x4 o = { (bf16)v.x, (bf16)v.y, (bf16)v.z, (bf16)v.w };
        ((bf16x4*)xb)[i] = o;
        return;
    }
    __shared__ float tile[64][65];
    const float* in; bf16* out; int C, bx;
    if (blk < 8192 + 3072) { bx = blk - 8192; in = Wqkv; out = WqkvT; C = D3_; }
    else                   { bx = blk - 8192 - 3072; in = Wproj; out = WprojT; C = D_; }
    const int R = D_;
    int nbx = C / 64;
    int c0 = (bx % nbx) * 64, r0 = (bx / nbx) * 64;
#pragma unroll
    for (int i = 0; i < 16; i++) {
        int idx = tid + i * 256, r = idx >> 6, c = idx & 63;
        tile[r][c] = in[(size_t)(r0 + r) * C + (c0 + c)];
    }
    __syncthreads();
#pragma unroll
    for (int i = 0; i < 16; i++) {
        int idx = tid + i * 256, r = idx >> 6, c = idx & 63;
        out[(size_t)(c0 + r) * R + (r0 + c)] = (bf16)tile[c][r];
    }
}

// ---------------- QKV GEMM with fused RoPE + scatter epilogue (R4 form) ----------------
__global__ __launch_bounds__(256) void k_gemm_qkv(const bf16* __restrict__ A, const bf16* __restrict__ Bt,
                                                  const float* __restrict__ cosp, const float* __restrict__ sinp,
                                                  bf16* __restrict__ Qg, bf16* __restrict__ Kg, f16* __restrict__ VTg) {
    __shared__ bf16 As[128 * 32];
    __shared__ bf16 Bs[128 * 32];
    __shared__ bf16 stage[128 * 130];
    const int tid = threadIdx.x, w = tid >> 6, lane = tid & 63;
    const int quad = lane >> 4, l16 = lane & 15;
    const int n0 = blockIdx.x * 128, m0 = blockIdx.y * 128;
    const int wr = (w >> 1) * 64, wc = (w & 1) * 64;
    const int srow = lane >> 2, schunk = (lane & 3) ^ ((lane >> 2) & 3);
    const bf16* Aw = A + (size_t)m0 * D_ + (size_t)(w * 32 + srow) * D_ + schunk * 8;
    const bf16* Bw = Bt + (size_t)n0 * D_ + (size_t)(w * 32 + srow) * D_ + schunk * 8;
    const int co = (quad ^ (l16 & 3)) * 8;
    const bf16* Abase = As + (wr + l16) * 32 + co;
    const bf16* Bbase = Bs + (wc + l16) * 32 + co;
    floatx4 acc[4][4] = {};
    for (int k0 = 0; k0 < D_; k0 += 32) {
        __syncthreads();
#pragma unroll
        for (int i = 0; i < 2; i++) {
            gl_lds16(Aw + k0 + i * 16 * D_, As + (w * 2 + i) * 512);
            gl_lds16(Bw + k0 + i * 16 * D_, Bs + (w * 2 + i) * 512);
        }
        __syncthreads();
        bf16x8 af[4], bfr[4];
#pragma unroll
        for (int mt = 0; mt < 4; mt++) af[mt] = *(const bf16x8*)(Abase + mt * 512);
#pragma unroll
        for (int nt = 0; nt < 4; nt++) bfr[nt] = *(const bf16x8*)(Bbase + nt * 512);
#pragma unroll
        for (int mt = 0; mt < 4; mt++)
#pragma unroll
            for (int nt = 0; nt < 4; nt++)
                acc[mt][nt] = __builtin_amdgcn_mfma_f32_16x16x32_bf16(af[mt], bfr[nt], acc[mt][nt], 0, 0, 0);
    }
    // stage C tile (bf16) into LDS
    __syncthreads();
#pragma unroll
    for (int mt = 0; mt < 4; mt++)
#pragma unroll
        for (int nt = 0; nt < 4; nt++)
#pragma unroll
            for (int r = 0; r < 4; r++)
                stage[(wr + mt * 16 + quad * 4 + r) * 130 + wc + nt * 16 + l16] = (bf16)acc[mt][nt][r];
    __syncthreads();
    const int type = n0 >> 11, h = (n0 & 2047) >> 7;
    const int b = m0 >> 11, t0 = m0 & 2047;
    if (type < 2) {
        bf16* out = (type == 0 ? Qg : Kg) + ((size_t)(b * H_ + h) * T_ + t0) * HD_;
#pragma unroll
        for (int it = 0; it < 32; it++) {
            int idx = it * 256 + tid, tl = idx >> 6, i = idx & 63;
            float c = cosp[(t0 + tl) * 64 + i], s = sinp[(t0 + tl) * 64 + i];
            float x1 = (float)stage[tl * 130 + i], x2 = (float)stage[tl * 130 + 64 + i];
            bf16x2 o = { (bf16)(x1 * c - x2 * s), (bf16)(x1 * s + x2 * c) };
            *(bf16x2*)(out + (size_t)tl * HD_ + 2 * i) = o;
        }
    } else {
        f16* out = VTg + (size_t)(b * H_ + h) * HD_ * T_ + t0;
#pragma unroll
        for (int it = 0; it < 32; it++) {
            int idx = it * 256 + tid, d = idx >> 6, tp = (idx & 63) * 2;
            f16x2 o = { (f16)(float)stage[tp * 130 + d], (f16)(float)stage[(tp + 1) * 130 + d] };
            *(f16x2*)(out + (size_t)d * T_ + tp) = o;
        }
    }
}

// ---------------- bf16 GEMM (proj): BK=64 XOR-swizzled (R5/R6 form — best measured proj) ----------------
template <typename OutT>
__global__ __launch_bounds__(256) void k_gemm_bt(const bf16* __restrict__ A, const bf16* __restrict__ Bt,
                                                 OutT* __restrict__ C, int M, int N, int K) {
    __shared__ bf16 As[128 * 64];
    __shared__ bf16 Bs[128 * 64];
    const int tid = threadIdx.x, w = tid >> 6, lane = tid & 63;
    const int quad = lane >> 4, l16 = lane & 15;
    const int x7 = l16 & 7;
    const int n0 = blockIdx.x * 128, m0 = blockIdx.y * 128;
    const int wr = (w >> 1) * 64, wc = (w & 1) * 64;
    const bf16* Ab = A + (size_t)m0 * K;
    const bf16* Bb = Bt + (size_t)n0 * K;
    const int srow = lane >> 3, schunk = (lane & 7) ^ (lane >> 3);
    floatx4 acc[4][4] = {};
    for (int k0 = 0; k0 < K; k0 += 64) {
        __syncthreads();
#pragma unroll
        for (int i = 0; i < 4; i++) {
            int ch = w * 4 + i;
            int row = ch * 8 + srow;
            gl_lds16(Ab + (size_t)row * K + k0 + schunk * 8, As + ch * 512);
            gl_lds16(Bb + (size_t)row * K + k0 + schunk * 8, Bs + ch * 512);
        }
        __syncthreads();
#pragma unroll
        for (int kc = 0; kc < 2; kc++) {
            const int co = ((kc * 4 + quad) ^ x7) * 8;
            const bf16* Abase = As + (wr + l16) * 64 + co;
            const bf16* Bbase = Bs + (wc + l16) * 64 + co;
            bf16x8 af[4], bfr[4];
#pragma unroll
            for (int mt = 0; mt < 4; mt++) af[mt] = *(const bf16x8*)(Abase + mt * 1024);
#pragma unroll
            for (int nt = 0; nt < 4; nt++) bfr[nt] = *(const bf16x8*)(Bbase + nt * 1024);
#pragma unroll
            for (int mt = 0; mt < 4; mt++)
#pragma unroll
                for (int nt = 0; nt < 4; nt++)
                    acc[mt][nt] = __builtin_amdgcn_mfma_f32_16x16x32_bf16(af[mt], bfr[nt], acc[mt][nt], 0, 0, 0);
        }
    }
#pragma unroll
    for (int mt = 0; mt < 4; mt++)
#pragma unroll
        for (int nt = 0; nt < 4; nt++)
#pragma unroll
            for (int r = 0; r < 4; r++) {
                int row = m0 + wr + mt * 16 + quad * 4 + r;
                int col = n0 + wc + nt * 16 + l16;
                C[(size_t)row * N + col] = (OutT)acc[mt][nt][r];
            }
}

// ---------------- Flash attention (R4 form: single-buffer, 2 barriers, S^T register path) ----------------
__global__ __launch_bounds__(256, 2) void k_flash(const bf16* __restrict__ Qg, const bf16* __restrict__ Kg,
                                                  const f16* __restrict__ VTg, bf16* __restrict__ Og) {
    __shared__ bf16 Ksh[64 * 128];      // K tile: 64 t x 128 d, XOR-swizzled 16B chunks
    __shared__ f16  Vsh[128 * 64];      // V^T tile: 128 d x 64 t, XOR-swizzled
    const int b1 = blockIdx.x;
    const int bh = b1 & 31;
    const int qt = (b1 < 256) ? (15 - (b1 >> 5)) : ((b1 - 256) >> 5);
    const int tid = threadIdx.x, w = tid >> 6, lane = tid & 63;
    const int quad = lane >> 4, l16 = lane & 15;
    const float scale2 = 0.08838834764831845f * 1.4426950408889634f;  // (1/sqrt(128))*log2(e)
    const int wrow = w * 32;
    const bf16* Qb = Qg + ((size_t)bh * T_ + qt * 128) * HD_;
    bf16x8 qf[2][4];
#pragma unroll
    for (int mt = 0; mt < 2; mt++)
#pragma unroll
        for (int kc = 0; kc < 4; kc++)
            qf[mt][kc] = *(const bf16x8*)(Qb + (size_t)(wrow + mt * 16 + l16) * HD_ + kc * 32 + quad * 8);
    floatx4 oaccT[8][2] = {};   // [d-tile][q-tile]: col=l16=query, row=quad*4+r=d
    float lsum[2] = { 0.f, 0.f };
    const int nkt = 2 * (qt + 1);
    for (int kt = 0; kt < nkt; kt++) {
        __syncthreads();
        const bf16* Kt = Kg + ((size_t)bh * T_ + kt * 64) * HD_;
        const f16*  Vt = VTg + (size_t)bh * HD_ * T_ + kt * 64;
#pragma unroll
        for (int i = 0; i < 4; i++) {
            int ch = w * 4 + i;
            {
                int row = ch * 4 + (lane >> 4);
                int c = (lane & 15) ^ (row & 7);
                gl_lds16(Kt + (size_t)row * HD_ + c * 8, Ksh + ch * 512);
            }
            {
                int row = ch * 8 + (lane >> 3);
                int c = (lane & 7) ^ (row & 7);
                gl_lds16(Vt + (size_t)row * T_ + c * 8, Vsh + ch * 512);
            }
        }
        __syncthreads();
        const bool diag = (kt >= 2 * qt);
        f16x4 pf[2][4];
#pragma unroll
        for (int nt = 0; nt < 4; nt++) {
            floatx4 s0 = {}, s1 = {};
#pragma unroll
            for (int kc = 0; kc < 4; kc++) {
                bf16x8 kf = *(const bf16x8*)(Ksh + (nt * 16 + l16) * 128 + (((kc * 4 + quad) ^ (l16 & 7)) * 8));
                s0 = __builtin_amdgcn_mfma_f32_16x16x32_bf16(kf, qf[0][kc], s0, 0, 0, 0);
                s1 = __builtin_amdgcn_mfma_f32_16x16x32_bf16(kf, qf[1][kc], s1, 0, 0, 0);
            }
#pragma unroll
            for (int r = 0; r < 4; r++) {
                float v0 = s0[r] * scale2, v1 = s1[r] * scale2;
                if (diag) {
                    int gk = kt * 64 + nt * 16 + quad * 4 + r;
                    if (gk > qt * 128 + wrow + l16) v0 = -1e30f;
                    if (gk > qt * 128 + wrow + 16 + l16) v1 = -1e30f;
                }
                float p0 = exp2f(v0), p1 = exp2f(v1);
                lsum[0] += p0; lsum[1] += p1;
                pf[0][nt][r] = (f16)p0; pf[1][nt][r] = (f16)p1;
            }
        }
        // O^T += V^T P^T  (16x16x16 f16 MFMA)
#pragma unroll
        for (int nt = 0; nt < 4; nt++)
#pragma unroll
            for (int dt = 0; dt < 8; dt++) {
                int row = dt * 16 + l16;
                f16x4 vf = *(const f16x4*)(Vsh + row * 64 + (((nt * 2 + (quad >> 1)) ^ (row & 7)) * 8) + (quad & 1) * 4);
#pragma unroll
                for (int mt = 0; mt < 2; mt++)
                    oaccT[dt][mt] = __builtin_amdgcn_mfma_f32_16x16x16f16(vf, pf[mt][nt], oaccT[dt][mt], 0, 0, 0);
            }
    }
    // epilogue
    const int b = bh >> 4, h = bh & 15;
    float inv[2];
#pragma unroll
    for (int mt = 0; mt < 2; mt++) {
        float l = lsum[mt];
        l += __shfl_xor(l, 16);
        l += __shfl_xor(l, 32);
        inv[mt] = 1.0f / l;
    }
#pragma unroll
    for (int mt = 0; mt < 2; mt++) {
        int t = qt * 128 + wrow + mt * 16 + l16;
#pragma unroll
        for (int dt = 0; dt < 8; dt++) {
            bf16x4 o;
#pragma unroll
            for (int r = 0; r < 4; r++) o[r] = (bf16)(oaccT[dt][mt][r] * inv[mt]);
            int c = h * HD_ + dt * 16 + quad * 4;
            *(bf16x4*)(Og + (size_t)(b * T_ + t) * D_ + c) = o;
        }
    }
}

extern "C" void kernel_launch(void* const* d_in, const int* in_sizes, int n_in,
                              void* d_out, int out_size, void* d_ws, size_t ws_size,
                              hipStream_t stream) {
    const float* x     = (const float*)d_in[0];
    const float* cosp  = (const float*)d_in[1];
    const float* sinp  = (const float*)d_in[2];
    const float* Wqkv  = (const float*)d_in[3];
    const float* Wproj = (const float*)d_in[4];
    float* out = (float*)d_out;
    char* ws = (char*)d_ws;
    // workspace layout (96 MB total)
    bf16* xb     = (bf16*)(ws);                          // 16 MB (reused as O after GEMM1)
    bf16* WqkvT  = (bf16*)(ws + (size_t)(16u << 20));    // 24 MB
    bf16* WprojT = (bf16*)(ws + (size_t)(40u << 20));    //  8 MB
    bf16* Qg     = (bf16*)(ws + (size_t)(48u << 20));    // 16 MB
    bf16* Kg     = (bf16*)(ws + (size_t)(64u << 20));    // 16 MB
    f16*  VTg    = (f16*) (ws + (size_t)(80u << 20));    // 16 MB
    bf16* Og     = xb;

    k_prep<<<dim3(8192 + 3072 + 1024), 256, 0, stream>>>(x, Wqkv, Wproj, xb, WqkvT, WprojT);
    k_gemm_qkv<<<dim3(D3_ / 128, NT_ / 128), 256, 0, stream>>>(xb, WqkvT, cosp, sinp, Qg, Kg, VTg);
    k_flash<<<dim3(512), 256, 0, stream>>>(Qg, Kg, VTg, Og);
    k_gemm_bt<float><<<dim3(D_ / 128, NT_ / 128), 256, 0, stream>>>(Og, WprojT, out, NT_, D_, D_);
}